// Round 10
// baseline (84.915 us; speedup 1.0000x reference)
//
#include <hip/hip_runtime.h>
#include <hip/hip_bf16.h>

#define S_LEN 127
#define NB    32
#define HDIM  256
#define DH    64
#define SCALE_F 0.125f

typedef __bf16 bf16x8 __attribute__((ext_vector_type(8)));
typedef __bf16 bf16x4 __attribute__((ext_vector_type(4)));
typedef float  f32x4  __attribute__((ext_vector_type(4)));

#define NTOK  4064                 // NB * S_LEN
#define NW4   16384                // 256*256/4 float4 groups per W

__device__ __forceinline__ float4 b2f4(bf16x4 v) {
  return make_float4((float)v[0], (float)v[1], (float)v[2], (float)v[3]);
}

// ---------------------------------------------------------------------------
// W-only f32 -> bf16 conversion (4 x 256x256). 256 blocks x 256 thr.
// ---------------------------------------------------------------------------
__global__ __launch_bounds__(256) void convert_w(
    const float* __restrict__ Wq, const float* __restrict__ Wk,
    const float* __restrict__ Wv, const float* __restrict__ Wo,
    __bf16* __restrict__ Wqb, __bf16* __restrict__ Wkb,
    __bf16* __restrict__ Wvb, __bf16* __restrict__ Wob)
{
  size_t t = (size_t)blockIdx.x * 256 + threadIdx.x;   // float4 index
  const float* src; __bf16* dst;
  if (t < NW4)                 { src = Wq; dst = Wqb; }
  else if ((t -= NW4) < NW4)   { src = Wk; dst = Wkb; }
  else if ((t -= NW4) < NW4)   { src = Wv; dst = Wvb; }
  else { t -= NW4;               src = Wo; dst = Wob; }
  const float4 x = ((const float4*)src)[t];
  bf16x4 r;
  r[0] = (__bf16)x.x; r[1] = (__bf16)x.y; r[2] = (__bf16)x.z; r[3] = (__bf16)x.w;
  ((bf16x4*)dst)[t] = r;
}

// ---------------------------------------------------------------------------
// q/k/v projection with in-LDS A conversion (R8-proven). grid (127,3), 256 thr.
// ---------------------------------------------------------------------------
__global__ __launch_bounds__(256) void gemm_qkv(
    const float* __restrict__ q_in, const float* __restrict__ k_in,
    const float* __restrict__ v_in,
    const __bf16* __restrict__ Wqb, const float* __restrict__ bq,
    const __bf16* __restrict__ Wkb, const float* __restrict__ bk,
    const __bf16* __restrict__ Wvb, const float* __restrict__ bv,
    __bf16* __restrict__ qpb, __bf16* __restrict__ kpb, __bf16* __restrict__ vpb)
{
  const int tile = blockIdx.x;       // 0..126
  const float* A; const __bf16* W; const float* bias; __bf16* o;
  if (blockIdx.y == 0)      { A = q_in; W = Wqb; bias = bq; o = qpb; }
  else if (blockIdx.y == 1) { A = k_in; W = Wkb; bias = bk; o = kpb; }
  else                      { A = v_in; W = Wvb; bias = bv; o = vpb; }

  __shared__ __bf16 sA[32][264];
  const int row0 = tile * 32;

#pragma unroll
  for (int j = 0; j < 8; ++j) {
    const int f = threadIdx.x + j * 256;   // 0..2047
    const int rr = f >> 6, c4 = f & 63;
    const float4 x = *(const float4*)(A + (size_t)(row0 + rr) * HDIM + c4 * 4);
    __bf16* d = &sA[rr][c4 * 4];
    d[0] = (__bf16)x.x; d[1] = (__bf16)x.y; d[2] = (__bf16)x.z; d[3] = (__bf16)x.w;
  }
  __syncthreads();

  const int w    = threadIdx.x >> 6;
  const int lane = threadIdx.x & 63;
  const int r    = lane & 15;
  const int ksl  = (lane >> 4) << 3;
  const int wc   = w * 64;

  const __bf16* Wb = W + (size_t)(wc + r) * HDIM + ksl;
  f32x4 acc[2][4] = {};

  bf16x8 cw[4];
#pragma unroll
  for (int ni = 0; ni < 4; ++ni)
    cw[ni] = *(const bf16x8*)(Wb + (size_t)ni * 16 * HDIM);
#pragma unroll
  for (int kb = 0; kb < 8; ++kb) {
    bf16x8 nw[4];
    if (kb < 7) {
#pragma unroll
      for (int ni = 0; ni < 4; ++ni)
        nw[ni] = *(const bf16x8*)(Wb + (size_t)ni * 16 * HDIM + (kb + 1) * 32);
    }
    const bf16x8 a0 = *(const bf16x8*)&sA[r][kb * 32 + ksl];
    const bf16x8 a1 = *(const bf16x8*)&sA[16 + r][kb * 32 + ksl];
#pragma unroll
    for (int ni = 0; ni < 4; ++ni) {
      acc[0][ni] = __builtin_amdgcn_mfma_f32_16x16x32_bf16(a0, cw[ni], acc[0][ni], 0, 0, 0);
      acc[1][ni] = __builtin_amdgcn_mfma_f32_16x16x32_bf16(a1, cw[ni], acc[1][ni], 0, 0, 0);
    }
    if (kb < 7) {
#pragma unroll
      for (int ni = 0; ni < 4; ++ni) cw[ni] = nw[ni];
    }
  }
  const int crow = (lane >> 4) * 4;
  const int ccol = lane & 15;
#pragma unroll
  for (int mi = 0; mi < 2; ++mi)
#pragma unroll
    for (int ni = 0; ni < 4; ++ni) {
      const int oc = wc + ni * 16 + ccol;
      const float bv = bias[oc];
#pragma unroll
      for (int rg = 0; rg < 4; ++rg)
        o[(size_t)(row0 + mi * 16 + crow + rg) * HDIM + oc] =
            (__bf16)(acc[mi][ni][rg] + bv);
    }
}

// ---------------------------------------------------------------------------
// Fused attention + out-projection. 1016 blocks x 1024 threads.
// 256-thread group s (0..3) runs the R8-proven attention for one item;
// x rows land in a 16-row LDS tile; then 16 waves MFMA against Wo (L2-hot)
// and write the final output. Barrier counts are uniform across groups.
// ---------------------------------------------------------------------------
__global__ __launch_bounds__(1024) void attn_o(
    const __bf16* __restrict__ qpb, const __bf16* __restrict__ kpb,
    const __bf16* __restrict__ vpb, const int* __restrict__ graph,
    const float* __restrict__ ekt, const float* __restrict__ evt,
    const float* __restrict__ eqt,
    const __bf16* __restrict__ Wob, const float* __restrict__ bo,
    float* __restrict__ out)
{
  const int s  = threadIdx.x >> 8;   // item slot 0..3
  const int t  = threadIdx.x & 255;  // local tid within item group
  const int w  = t >> 6;             // wave-role 0..3 within group
  const int l  = t & 63;             // lane
  const int ll = l & 15;             // d-subgroup
  const int g  = l >> 4;             // column slot 0..3

  __shared__ int    s_list[4][S_LEN];
  __shared__ float  s_attn[4][4][S_LEN];
  __shared__ int    s_cnt[4][2];
  __shared__ int    s_tok[4];
  __shared__ __bf16 x_lds[16][264];

  // zero x rows 4-15 (A-frag padding rows for the 16x16 MFMA)
  for (int z = threadIdx.x; z < 12 * 264; z += 1024) {
    const int zr = z / 264;
    x_lds[4 + zr][z - zr * 264] = (__bf16)0.f;
  }

  // item for this group: strided so long-poles (first 96 ids) spread 1/block
  const int item = blockIdx.x + s * 1016;
  int b, q;
  if (item < 96) { b = item / 3; q = item % 3; }
  else { const int rr = item - 96; b = rr / 124; q = 3 + rr % 124; }
  if (t == 0) s_tok[s] = b * S_LEN + q;

  // ---- compacted valid-k list (waves 0,1 of the group) ----
  bool valid = false;
  const int k0 = w * 64 + l;
  if (w < 2 && k0 < S_LEN) {
    const int gr = graph[((size_t)b * S_LEN + q) * S_LEN + k0];
    bool keep;
    if (q < 3 || k0 < 3) keep = true;
    else {
      const int blk = 3 + 2 * ((q - 3) >> 1);
      keep = (k0 >= blk) & (k0 < blk + 2);
    }
    valid = (gr != 0) && keep;
  }
  const unsigned long long bal = __ballot(valid);
  if (w < 2 && l == 0) s_cnt[s][w] = (int)__popcll(bal);
  __syncthreads();                                        // (A)
  int n = s_cnt[s][0] + s_cnt[s][1];
  if (valid) {
    const int pos = (int)__popcll(bal & ((1ull << l) - 1ull)) + (w ? s_cnt[s][0] : 0);
    s_list[s][pos] = k0;
  }
  __syncthreads();                                        // (B)

  const bool uni = (n == 0);
  if (uni) {
    if (t < S_LEN) {
      s_list[s][t] = t;
      const float u = 1.0f / 127.0f;
      s_attn[s][0][t] = u; s_attn[s][1][t] = u;
      s_attn[s][2][t] = u; s_attn[s][3][t] = u;
    }
    n = S_LEN;
  } else {
    // ---- scores: group-(w,g) owns column i0 + w*4 + g, prefetched ----
    const __bf16* qrow = qpb + ((size_t)b * S_LEN + q) * HDIM;
    float4 q4[4];
#pragma unroll
    for (int h = 0; h < 4; ++h)
      q4[h] = b2f4(*(const bf16x4*)(qrow + h * 64 + ll * 4));
    const float* eqb2 = eqt + ((size_t)b * S_LEN * S_LEN + q) * DH;
    const float* ekb2 = ekt + ((size_t)(b * S_LEN + q)) * S_LEN * DH;
    const __bf16* kpbb = kpb + (size_t)b * S_LEN * HDIM;
    const int myi = w * 4 + g;

    float4 ceq, cek;
    bf16x4 ck0, ck1, ck2, ck3;
    if (myi < n) {
      const int kk = s_list[s][myi];
      ceq = *(const float4*)(eqb2 + (size_t)kk * (S_LEN * DH) + ll * 4);
      cek = *(const float4*)(ekb2 + kk * DH + ll * 4);
      const __bf16* kr = kpbb + (size_t)kk * HDIM + ll * 4;
      ck0 = *(const bf16x4*)(kr);
      ck1 = *(const bf16x4*)(kr + 64);
      ck2 = *(const bf16x4*)(kr + 128);
      ck3 = *(const bf16x4*)(kr + 192);
    }
    for (int i0 = 0; i0 < n; i0 += 16) {
      const int i = i0 + myi;
      float4 neq, nek;
      bf16x4 nk0, nk1, nk2, nk3;
      const int j = i + 16;
      if (j < n) {
        const int kk = s_list[s][j];
        neq = *(const float4*)(eqb2 + (size_t)kk * (S_LEN * DH) + ll * 4);
        nek = *(const float4*)(ekb2 + kk * DH + ll * 4);
        const __bf16* kr = kpbb + (size_t)kk * HDIM + ll * 4;
        nk0 = *(const bf16x4*)(kr);
        nk1 = *(const bf16x4*)(kr + 64);
        nk2 = *(const bf16x4*)(kr + 128);
        nk3 = *(const bf16x4*)(kr + 192);
      }
      float p0 = 0.f, p1 = 0.f, p2 = 0.f, p3 = 0.f;
      if (i < n) {
        const float4 k0f = b2f4(ck0), k1f = b2f4(ck1),
                     k2f = b2f4(ck2), k3f = b2f4(ck3);
        p0 = (q4[0].x+ceq.x)*(k0f.x+cek.x) + (q4[0].y+ceq.y)*(k0f.y+cek.y)
           + (q4[0].z+ceq.z)*(k0f.z+cek.z) + (q4[0].w+ceq.w)*(k0f.w+cek.w);
        p1 = (q4[1].x+ceq.x)*(k1f.x+cek.x) + (q4[1].y+ceq.y)*(k1f.y+cek.y)
           + (q4[1].z+ceq.z)*(k1f.z+cek.z) + (q4[1].w+ceq.w)*(k1f.w+cek.w);
        p2 = (q4[2].x+ceq.x)*(k2f.x+cek.x) + (q4[2].y+ceq.y)*(k2f.y+cek.y)
           + (q4[2].z+ceq.z)*(k2f.z+cek.z) + (q4[2].w+ceq.w)*(k2f.w+cek.w);
        p3 = (q4[3].x+ceq.x)*(k3f.x+cek.x) + (q4[3].y+ceq.y)*(k3f.y+cek.y)
           + (q4[3].z+ceq.z)*(k3f.z+cek.z) + (q4[3].w+ceq.w)*(k3f.w+cek.w);
      }
#pragma unroll
      for (int off = 1; off < 16; off <<= 1) {
        p0 += __shfl_xor(p0, off, 64);
        p1 += __shfl_xor(p1, off, 64);
        p2 += __shfl_xor(p2, off, 64);
        p3 += __shfl_xor(p3, off, 64);
      }
      if (i < n && ll < 4) {
        const float sc = (ll == 0) ? p0 : (ll == 1) ? p1 : (ll == 2) ? p2 : p3;
        s_attn[s][ll][i] = sc * SCALE_F;
      }
      ceq = neq; cek = nek;
      ck0 = nk0; ck1 = nk1; ck2 = nk2; ck3 = nk3;
    }
  }
  __syncthreads();                                        // (C)

  if (!uni) {
    // ---- softmax per head: wave-role w over n compacted scores ----
    const float v0 = (l < n) ? s_attn[s][w][l] : -INFINITY;
    const float v1 = (64 + l < n) ? s_attn[s][w][64 + l] : -INFINITY;
    float mx = fmaxf(v0, v1);
#pragma unroll
    for (int off = 32; off; off >>= 1) mx = fmaxf(mx, __shfl_xor(mx, off, 64));
    const float e0 = (l < n) ? expf(v0 - mx) : 0.f;
    const float e1 = (64 + l < n) ? expf(v1 - mx) : 0.f;
    float sm = e0 + e1;
#pragma unroll
    for (int off = 32; off; off >>= 1) sm += __shfl_xor(sm, off, 64);
    const float inv = 1.0f / sm;
    if (l < n) s_attn[s][w][l] = e0 * inv;
    if (64 + l < n) s_attn[s][w][64 + l] = e1 * inv;
  }
  __syncthreads();                                        // (D)

  // ---- PV: wave-role w = head; group g handles cols g, g+4, ...; prefetched ----
  {
    const float* evb2 = evt + ((size_t)(b * S_LEN + q)) * S_LEN * DH;
    const __bf16* vbp = vpb + (size_t)b * S_LEN * HDIM + w * DH + ll * 4;
    float ax = 0.f, ay = 0.f, az = 0.f, aw2 = 0.f;

    int i = g;
    float a = 0.f; bf16x4 v4; float4 e4;
    if (i < n) {
      const int kk = s_list[s][i];
      a = s_attn[s][w][i];
      v4 = *(const bf16x4*)(vbp + (size_t)kk * HDIM);
      e4 = *(const float4*)(evb2 + kk * DH + ll * 4);
    }
    while (i < n) {
      const int j = i + 4;
      float a2 = 0.f; bf16x4 v42; float4 e42;
      if (j < n) {
        const int kk = s_list[s][j];
        a2 = s_attn[s][w][j];
        v42 = *(const bf16x4*)(vbp + (size_t)kk * HDIM);
        e42 = *(const float4*)(evb2 + kk * DH + ll * 4);
      }
      const float4 vf = b2f4(v4);
      ax  += a * (vf.x + e4.x);
      ay  += a * (vf.y + e4.y);
      az  += a * (vf.z + e4.z);
      aw2 += a * (vf.w + e4.w);
      i = j; a = a2; v4 = v42; e4 = e42;
    }
#pragma unroll
    for (int off = 16; off < 64; off <<= 1) {
      ax  += __shfl_xor(ax, off, 64);
      ay  += __shfl_xor(ay, off, 64);
      az  += __shfl_xor(az, off, 64);
      aw2 += __shfl_xor(aw2, off, 64);
    }
    if (g == 0) {
      bf16x4 rr;
      rr[0] = (__bf16)ax; rr[1] = (__bf16)ay;
      rr[2] = (__bf16)az; rr[3] = (__bf16)aw2;
      *(bf16x4*)&x_lds[s][w * 64 + ll * 4] = rr;
    }
  }
  __syncthreads();                                        // (E)

  // ---- out-projection: 16 waves, each a 16-col strip of out[4 items, 256] ----
  {
    const int wav  = threadIdx.x >> 6;    // 0..15
    const int lane = threadIdx.x & 63;
    const int r    = lane & 15;
    const int ks   = (lane >> 4) << 3;
    const int c0   = wav * 16;
    const __bf16* Wb = Wob + (size_t)(c0 + r) * HDIM + ks;
    f32x4 acc = {};
    bf16x8 cw = *(const bf16x8*)Wb;
#pragma unroll
    for (int kb = 0; kb < 8; ++kb) {
      bf16x8 nw;
      if (kb < 7) nw = *(const bf16x8*)(Wb + (kb + 1) * 32);
      const bf16x8 a = *(const bf16x8*)&x_lds[r][kb * 32 + ks];
      acc = __builtin_amdgcn_mfma_f32_16x16x32_bf16(a, cw, acc, 0, 0, 0);
      if (kb < 7) cw = nw;
    }
    // C rows 0-3 live in lanes 0-15 (row = rg), col = c0 + r
    if ((lane >> 4) == 0) {
      const float bv = bo[c0 + r];
#pragma unroll
      for (int rg = 0; rg < 4; ++rg)
        out[(size_t)s_tok[rg] * HDIM + c0 + r] = acc[rg] + bv;
    }
  }
}

extern "C" void kernel_launch(void* const* d_in, const int* in_sizes, int n_in,
                              void* d_out, int out_size, void* d_ws, size_t ws_size,
                              hipStream_t stream) {
  const float* query = (const float*)d_in[0];
  const float* key   = (const float*)d_in[1];
  const float* value = (const float*)d_in[2];
  const int*   graph = (const int*)d_in[3];
  const float* ekt   = (const float*)d_in[4];
  const float* evt   = (const float*)d_in[5];
  const float* eqt   = (const float*)d_in[6];
  const float* Wq = (const float*)d_in[7];  const float* bq = (const float*)d_in[8];
  const float* Wk = (const float*)d_in[9];  const float* bk = (const float*)d_in[10];
  const float* Wv = (const float*)d_in[11]; const float* bv = (const float*)d_in[12];
  const float* Wo = (const float*)d_in[13]; const float* bo = (const float*)d_in[14];
  float* out = (float*)d_out;

  const size_t NE = (size_t)NTOK * HDIM;   // 1,040,384 elems
  char* p = (char*)d_ws;
  __bf16* qpb = (__bf16*)p;         p += NE * 2;
  __bf16* kpb = (__bf16*)p;         p += NE * 2;
  __bf16* vpb = (__bf16*)p;         p += NE * 2;
  __bf16* Wqb = (__bf16*)p;         p += (size_t)HDIM * HDIM * 2;
  __bf16* Wkb = (__bf16*)p;         p += (size_t)HDIM * HDIM * 2;
  __bf16* Wvb = (__bf16*)p;         p += (size_t)HDIM * HDIM * 2;
  __bf16* Wob = (__bf16*)p;

  convert_w<<<dim3(256), 256, 0, stream>>>(Wq, Wk, Wv, Wo, Wqb, Wkb, Wvb, Wob);
  gemm_qkv<<<dim3(127, 3), 256, 0, stream>>>(query, key, value,
                                             Wqb, bq, Wkb, bk, Wvb, bv,
                                             qpb, kpb, vpb);
  attn_o<<<dim3(1016), 1024, 0, stream>>>(qpb, kpb, vpb, graph,
                                          ekt, evt, eqt, Wob, bo, out);
}

// Round 11
// 56.581 us; speedup vs baseline: 1.5008x; 1.5008x over previous
//
#include <hip/hip_runtime.h>
#include <hip/hip_bf16.h>

#define S_LEN 127
#define NB    32
#define HDIM  256
#define DH    64
#define SCALE_F 0.125f
#define NEG_F  -100000.0f

typedef __bf16 bf16x8 __attribute__((ext_vector_type(8)));
typedef __bf16 bf16x4 __attribute__((ext_vector_type(4)));
typedef float  f32x4  __attribute__((ext_vector_type(4)));

#define NTOK  4064                 // NB * S_LEN
#define NW4   16384                // 256*256/4 float4 groups per W

__device__ __forceinline__ float4 b2f4(bf16x4 v) {
  return make_float4((float)v[0], (float)v[1], (float)v[2], (float)v[3]);
}

// ---------------------------------------------------------------------------
// W-only f32 -> bf16 conversion (R8-proven).
// ---------------------------------------------------------------------------
__global__ __launch_bounds__(256) void convert_w(
    const float* __restrict__ Wq, const float* __restrict__ Wk,
    const float* __restrict__ Wv, const float* __restrict__ Wo,
    __bf16* __restrict__ Wqb, __bf16* __restrict__ Wkb,
    __bf16* __restrict__ Wvb, __bf16* __restrict__ Wob)
{
  size_t t = (size_t)blockIdx.x * 256 + threadIdx.x;   // float4 index
  const float* src; __bf16* dst;
  if (t < NW4)                 { src = Wq; dst = Wqb; }
  else if ((t -= NW4) < NW4)   { src = Wk; dst = Wkb; }
  else if ((t -= NW4) < NW4)   { src = Wv; dst = Wvb; }
  else { t -= NW4;               src = Wo; dst = Wob; }
  const float4 x = ((const float4*)src)[t];
  bf16x4 r;
  r[0] = (__bf16)x.x; r[1] = (__bf16)x.y; r[2] = (__bf16)x.z; r[3] = (__bf16)x.w;
  ((bf16x4*)dst)[t] = r;
}

// ---------------------------------------------------------------------------
// q/k/v projection with in-LDS A conversion (R8-proven). grid (127,3), 256 thr.
// ---------------------------------------------------------------------------
__global__ __launch_bounds__(256) void gemm_qkv(
    const float* __restrict__ q_in, const float* __restrict__ k_in,
    const float* __restrict__ v_in,
    const __bf16* __restrict__ Wqb, const float* __restrict__ bq,
    const __bf16* __restrict__ Wkb, const float* __restrict__ bk,
    const __bf16* __restrict__ Wvb, const float* __restrict__ bv,
    __bf16* __restrict__ qpb, __bf16* __restrict__ kpb, __bf16* __restrict__ vpb)
{
  const int tile = blockIdx.x;       // 0..126
  const float* A; const __bf16* W; const float* bias; __bf16* o;
  if (blockIdx.y == 0)      { A = q_in; W = Wqb; bias = bq; o = qpb; }
  else if (blockIdx.y == 1) { A = k_in; W = Wkb; bias = bk; o = kpb; }
  else                      { A = v_in; W = Wvb; bias = bv; o = vpb; }

  __shared__ __bf16 sA[32][264];
  const int row0 = tile * 32;

#pragma unroll
  for (int j = 0; j < 8; ++j) {
    const int f = threadIdx.x + j * 256;   // 0..2047
    const int rr = f >> 6, c4 = f & 63;
    const float4 x = *(const float4*)(A + (size_t)(row0 + rr) * HDIM + c4 * 4);
    __bf16* d = &sA[rr][c4 * 4];
    d[0] = (__bf16)x.x; d[1] = (__bf16)x.y; d[2] = (__bf16)x.z; d[3] = (__bf16)x.w;
  }
  __syncthreads();

  const int w    = threadIdx.x >> 6;
  const int lane = threadIdx.x & 63;
  const int r    = lane & 15;
  const int ksl  = (lane >> 4) << 3;
  const int wc   = w * 64;

  const __bf16* Wb = W + (size_t)(wc + r) * HDIM + ksl;
  f32x4 acc[2][4] = {};

  bf16x8 cw[4];
#pragma unroll
  for (int ni = 0; ni < 4; ++ni)
    cw[ni] = *(const bf16x8*)(Wb + (size_t)ni * 16 * HDIM);
#pragma unroll
  for (int kb = 0; kb < 8; ++kb) {
    bf16x8 nw[4];
    if (kb < 7) {
#pragma unroll
      for (int ni = 0; ni < 4; ++ni)
        nw[ni] = *(const bf16x8*)(Wb + (size_t)ni * 16 * HDIM + (kb + 1) * 32);
    }
    const bf16x8 a0 = *(const bf16x8*)&sA[r][kb * 32 + ksl];
    const bf16x8 a1 = *(const bf16x8*)&sA[16 + r][kb * 32 + ksl];
#pragma unroll
    for (int ni = 0; ni < 4; ++ni) {
      acc[0][ni] = __builtin_amdgcn_mfma_f32_16x16x32_bf16(a0, cw[ni], acc[0][ni], 0, 0, 0);
      acc[1][ni] = __builtin_amdgcn_mfma_f32_16x16x32_bf16(a1, cw[ni], acc[1][ni], 0, 0, 0);
    }
    if (kb < 7) {
#pragma unroll
      for (int ni = 0; ni < 4; ++ni) cw[ni] = nw[ni];
    }
  }
  const int crow = (lane >> 4) * 4;
  const int ccol = lane & 15;
#pragma unroll
  for (int mi = 0; mi < 2; ++mi)
#pragma unroll
    for (int ni = 0; ni < 4; ++ni) {
      const int oc = wc + ni * 16 + ccol;
      const float bv = bias[oc];
#pragma unroll
      for (int rg = 0; rg < 4; ++rg)
        o[(size_t)(row0 + mi * 16 + crow + rg) * HDIM + oc] =
            (__bf16)(acc[mi][ni][rg] + bv);
    }
}

// ---------------------------------------------------------------------------
// Attention, list-free. Grid 1088 x 256:
//  blocks 0..95   : one block per q<3 item, all-127-column direct addressing.
//  blocks 96..1087: one WAVE per q>=3 item (5 static candidate columns
//                   {0,1,2,blk,blk+1}); mask5==0 -> uniform 1/127 over 127.
// Masked score = -1e5 -> exp underflows to exactly 0 when any valid col
// exists; all-masked -> all scores equal -> softmax exactly 1/127 (automatic).
// ---------------------------------------------------------------------------
__global__ __launch_bounds__(256) void attn_x(
    const __bf16* __restrict__ qpb, const __bf16* __restrict__ kpb,
    const __bf16* __restrict__ vpb, const int* __restrict__ graph,
    const float* __restrict__ ekt, const float* __restrict__ evt,
    const float* __restrict__ eqt, __bf16* __restrict__ xpb)
{
  const int w  = threadIdx.x >> 6;   // wave 0..3
  const int l  = threadIdx.x & 63;   // lane
  const int ll = l & 15;             // d-subgroup (score phase)
  const int g  = l >> 4;             // column slot (score phase)

  __shared__ float s_attn[4][S_LEN];
  __shared__ float s_mskf[S_LEN];
  __shared__ float s_sc[4][4][5];

  if (blockIdx.x < 96) {
    // ================= q<3 path: block per item, 127 columns =============
    const int b = blockIdx.x / 3, q = blockIdx.x % 3;

    if (w < 2) {
      const int k0 = w * 64 + l;
      if (k0 < S_LEN)
        s_mskf[k0] = (graph[((size_t)b * S_LEN + q) * S_LEN + k0] != 0) ? 1.f : 0.f;
    }
    __syncthreads();

    // ---- scores over all 127 columns, direct addressing ----
    const __bf16* qrow = qpb + ((size_t)b * S_LEN + q) * HDIM;
    float4 q4[4];
#pragma unroll
    for (int h = 0; h < 4; ++h)
      q4[h] = b2f4(*(const bf16x4*)(qrow + h * 64 + ll * 4));
    const float* eqb2 = eqt + ((size_t)b * S_LEN * S_LEN + q) * DH;
    const float* ekb2 = ekt + ((size_t)(b * S_LEN + q)) * S_LEN * DH;
    const __bf16* kpbb = kpb + (size_t)b * S_LEN * HDIM;

    for (int i0 = 0; i0 < S_LEN; i0 += 16) {
      const int i = i0 + w * 4 + g;
      float p0 = 0.f, p1 = 0.f, p2 = 0.f, p3 = 0.f;
      if (i < S_LEN) {
        const float4 eq4 = *(const float4*)(eqb2 + (size_t)i * (S_LEN * DH) + ll * 4);
        const float4 ek4 = *(const float4*)(ekb2 + (size_t)i * DH + ll * 4);
        const __bf16* kr = kpbb + (size_t)i * HDIM + ll * 4;
        const float4 k0f = b2f4(*(const bf16x4*)(kr));
        const float4 k1f = b2f4(*(const bf16x4*)(kr + 64));
        const float4 k2f = b2f4(*(const bf16x4*)(kr + 128));
        const float4 k3f = b2f4(*(const bf16x4*)(kr + 192));
        p0 = (q4[0].x+eq4.x)*(k0f.x+ek4.x) + (q4[0].y+eq4.y)*(k0f.y+ek4.y)
           + (q4[0].z+eq4.z)*(k0f.z+ek4.z) + (q4[0].w+eq4.w)*(k0f.w+ek4.w);
        p1 = (q4[1].x+eq4.x)*(k1f.x+ek4.x) + (q4[1].y+eq4.y)*(k1f.y+ek4.y)
           + (q4[1].z+eq4.z)*(k1f.z+ek4.z) + (q4[1].w+eq4.w)*(k1f.w+ek4.w);
        p2 = (q4[2].x+eq4.x)*(k2f.x+ek4.x) + (q4[2].y+eq4.y)*(k2f.y+ek4.y)
           + (q4[2].z+eq4.z)*(k2f.z+ek4.z) + (q4[2].w+eq4.w)*(k2f.w+ek4.w);
        p3 = (q4[3].x+eq4.x)*(k3f.x+ek4.x) + (q4[3].y+eq4.y)*(k3f.y+ek4.y)
           + (q4[3].z+eq4.z)*(k3f.z+ek4.z) + (q4[3].w+eq4.w)*(k3f.w+ek4.w);
      }
#pragma unroll
      for (int off = 1; off < 16; off <<= 1) {
        p0 += __shfl_xor(p0, off, 64);
        p1 += __shfl_xor(p1, off, 64);
        p2 += __shfl_xor(p2, off, 64);
        p3 += __shfl_xor(p3, off, 64);
      }
      if (i < S_LEN && ll < 4) {
        const float sc = (ll == 0) ? p0 : (ll == 1) ? p1 : (ll == 2) ? p2 : p3;
        s_attn[ll][i] = (s_mskf[i] != 0.f) ? sc * SCALE_F : NEG_F;
      }
    }
    __syncthreads();

    // ---- softmax per head over 127 ----
    {
      const float v0 = (l < S_LEN) ? s_attn[w][l] : -INFINITY;
      const float v1 = (64 + l < S_LEN) ? s_attn[w][64 + l] : -INFINITY;
      float mx = fmaxf(v0, v1);
#pragma unroll
      for (int off = 32; off; off >>= 1) mx = fmaxf(mx, __shfl_xor(mx, off, 64));
      const float e0 = (l < S_LEN) ? expf(v0 - mx) : 0.f;
      const float e1 = (64 + l < S_LEN) ? expf(v1 - mx) : 0.f;
      float sm = e0 + e1;
#pragma unroll
      for (int off = 32; off; off >>= 1) sm += __shfl_xor(sm, off, 64);
      const float inv = 1.0f / sm;
      if (l < S_LEN) s_attn[w][l] = e0 * inv;
      if (64 + l < S_LEN) s_attn[w][64 + l] = e1 * inv;
    }
    __syncthreads();

    // ---- PV over 127 (masked weights exactly 0; sequential addresses) ----
    {
      const float* evb2 = evt + ((size_t)(b * S_LEN + q)) * S_LEN * DH;
      const __bf16* vbp = vpb + (size_t)b * S_LEN * HDIM + w * DH + ll * 4;
      float ax = 0.f, ay = 0.f, az = 0.f, aw2 = 0.f;
#pragma unroll 4
      for (int i = g; i < S_LEN; i += 4) {
        const float a = s_attn[w][i];
        const float4 vf = b2f4(*(const bf16x4*)(vbp + (size_t)i * HDIM));
        const float4 e4 = *(const float4*)(evb2 + (size_t)i * DH + ll * 4);
        ax  += a * (vf.x + e4.x);
        ay  += a * (vf.y + e4.y);
        az  += a * (vf.z + e4.z);
        aw2 += a * (vf.w + e4.w);
      }
#pragma unroll
      for (int off = 16; off < 64; off <<= 1) {
        ax  += __shfl_xor(ax, off, 64);
        ay  += __shfl_xor(ay, off, 64);
        az  += __shfl_xor(az, off, 64);
        aw2 += __shfl_xor(aw2, off, 64);
      }
      if (g == 0) {
        bf16x4 rr;
        rr[0] = (__bf16)ax; rr[1] = (__bf16)ay;
        rr[2] = (__bf16)az; rr[3] = (__bf16)aw2;
        *(bf16x4*)(xpb + ((size_t)b * S_LEN + q) * HDIM + w * 64 + ll * 4) = rr;
      }
    }
  } else {
    // ================= q>=3 path: one wave per item ======================
    const int widx = (blockIdx.x - 96) * 4 + w;      // 0..3967
    const int b = widx / 124;
    const int q = 3 + widx % 124;
    const int blk = 3 + 2 * ((q - 3) >> 1);

    // 5 candidate columns: 0,1,2,blk,blk+1 (static given q)
    bool gb = false;
    if (l < 5) {
      const int c = (l < 3) ? l : blk + (l - 3);
      gb = graph[((size_t)b * S_LEN + q) * S_LEN + c] != 0;
    }
    const unsigned mask5 = (unsigned)(__ballot(gb) & 31ull);

    if (mask5) {
      const __bf16* qrow = qpb + ((size_t)b * S_LEN + q) * HDIM;
      float4 q4[4];
#pragma unroll
      for (int h = 0; h < 4; ++h)
        q4[h] = b2f4(*(const bf16x4*)(qrow + h * 64 + ll * 4));
      const float* eqb2 = eqt + ((size_t)b * S_LEN * S_LEN + q) * DH;
      const float* ekb2 = ekt + ((size_t)(b * S_LEN + q)) * S_LEN * DH;
      const __bf16* kpbb = kpb + (size_t)b * S_LEN * HDIM;

#pragma unroll
      for (int it = 0; it < 2; ++it) {
        const bool act = (it == 0) || (g == 0);
        const int ci = (it == 0) ? g : 4;
        const int c = (ci < 3) ? ci : blk + (ci - 3);
        float p0 = 0.f, p1 = 0.f, p2 = 0.f, p3 = 0.f;
        if (act) {
          const float4 eq4 = *(const float4*)(eqb2 + (size_t)c * (S_LEN * DH) + ll * 4);
          const float4 ek4 = *(const float4*)(ekb2 + (size_t)c * DH + ll * 4);
          const __bf16* kr = kpbb + (size_t)c * HDIM + ll * 4;
          const float4 k0f = b2f4(*(const bf16x4*)(kr));
          const float4 k1f = b2f4(*(const bf16x4*)(kr + 64));
          const float4 k2f = b2f4(*(const bf16x4*)(kr + 128));
          const float4 k3f = b2f4(*(const bf16x4*)(kr + 192));
          p0 = (q4[0].x+eq4.x)*(k0f.x+ek4.x) + (q4[0].y+eq4.y)*(k0f.y+ek4.y)
             + (q4[0].z+eq4.z)*(k0f.z+ek4.z) + (q4[0].w+eq4.w)*(k0f.w+ek4.w);
          p1 = (q4[1].x+eq4.x)*(k1f.x+ek4.x) + (q4[1].y+eq4.y)*(k1f.y+ek4.y)
             + (q4[1].z+eq4.z)*(k1f.z+ek4.z) + (q4[1].w+eq4.w)*(k1f.w+ek4.w);
          p2 = (q4[2].x+eq4.x)*(k2f.x+ek4.x) + (q4[2].y+eq4.y)*(k2f.y+ek4.y)
             + (q4[2].z+eq4.z)*(k2f.z+ek4.z) + (q4[2].w+eq4.w)*(k2f.w+ek4.w);
          p3 = (q4[3].x+eq4.x)*(k3f.x+ek4.x) + (q4[3].y+eq4.y)*(k3f.y+ek4.y)
             + (q4[3].z+eq4.z)*(k3f.z+ek4.z) + (q4[3].w+eq4.w)*(k3f.w+ek4.w);
        }
#pragma unroll
        for (int off = 1; off < 16; off <<= 1) {
          p0 += __shfl_xor(p0, off, 64);
          p1 += __shfl_xor(p1, off, 64);
          p2 += __shfl_xor(p2, off, 64);
          p3 += __shfl_xor(p3, off, 64);
        }
        if (act && ll < 4) {
          const float sc = (ll == 0) ? p0 : (ll == 1) ? p1 : (ll == 2) ? p2 : p3;
          s_sc[w][ll][ci] = ((mask5 >> ci) & 1) ? sc * SCALE_F : NEG_F;
        }
      }
    }
    __syncthreads();   // cross-lane LDS visibility (uniform across block)

    float acc0 = 0.f, acc1 = 0.f, acc2 = 0.f, acc3 = 0.f;
    const float* evb2 = evt + ((size_t)(b * S_LEN + q)) * S_LEN * DH;
    const __bf16* vrow_base = vpb + (size_t)b * S_LEN * HDIM;

    if (mask5) {
      // softmax per head over 5 (each lane redundantly; masked -> exactly 0)
      float wgt[4][5];
#pragma unroll
      for (int h = 0; h < 4; ++h) {
        float m = -INFINITY;
#pragma unroll
        for (int ci = 0; ci < 5; ++ci) m = fmaxf(m, s_sc[w][h][ci]);
        float sum = 0.f;
#pragma unroll
        for (int ci = 0; ci < 5; ++ci) {
          const float e = expf(s_sc[w][h][ci] - m);
          wgt[h][ci] = e; sum += e;
        }
        const float inv = 1.0f / sum;
#pragma unroll
        for (int ci = 0; ci < 5; ++ci) wgt[h][ci] *= inv;
      }
      // PV over the valid candidates; lane = d (0..63)
#pragma unroll
      for (int ci = 0; ci < 5; ++ci) {
        if (!((mask5 >> ci) & 1)) continue;
        const int c = (ci < 3) ? ci : blk + (ci - 3);
        const float ev = evb2[(size_t)c * DH + l];
        const __bf16* vr = vrow_base + (size_t)c * HDIM;
        acc0 += wgt[0][ci] * ((float)vr[l]       + ev);
        acc1 += wgt[1][ci] * ((float)vr[64 + l]  + ev);
        acc2 += wgt[2][ci] * ((float)vr[128 + l] + ev);
        acc3 += wgt[3][ci] * ((float)vr[192 + l] + ev);
      }
    } else {
      // all candidates masked -> uniform 1/127 over all 127 columns
#pragma unroll 4
      for (int c = 0; c < S_LEN; ++c) {
        const float ev = evb2[(size_t)c * DH + l];
        const __bf16* vr = vrow_base + (size_t)c * HDIM;
        acc0 += (float)vr[l]       + ev;
        acc1 += (float)vr[64 + l]  + ev;
        acc2 += (float)vr[128 + l] + ev;
        acc3 += (float)vr[192 + l] + ev;
      }
      const float u = 1.0f / 127.0f;
      acc0 *= u; acc1 *= u; acc2 *= u; acc3 *= u;
    }

    __bf16* xr = xpb + ((size_t)b * S_LEN + q) * HDIM;
    xr[l]       = (__bf16)acc0;
    xr[64 + l]  = (__bf16)acc1;
    xr[128 + l] = (__bf16)acc2;
    xr[192 + l] = (__bf16)acc3;
  }
}

// ---------------------------------------------------------------------------
// Output projection (R8-proven): per-wave 32x32 tile, bf16 A and W.
// ---------------------------------------------------------------------------
__global__ __launch_bounds__(256) void gemm_o(
    const __bf16* __restrict__ A, const __bf16* __restrict__ W,
    const float* __restrict__ bias, float* __restrict__ out)
{
  const int w = threadIdx.x >> 6;
  const int tile = blockIdx.x * 4 + w;
  if (tile >= 127) return;
  const int row0 = tile * 32, col0 = blockIdx.y * 32;
  const int lane = threadIdx.x & 63;
  const int r  = lane & 15;
  const int ks = (lane >> 4) << 3;
  const __bf16* Ab = A + (size_t)(row0 + r) * HDIM + ks;
  const __bf16* Wb = W + (size_t)(col0 + r) * HDIM + ks;
  f32x4 acc[2][2] = {};

  bf16x8 ca[2], cw[2];
  ca[0] = *(const bf16x8*)Ab;
  ca[1] = *(const bf16x8*)(Ab + (size_t)16 * HDIM);
  cw[0] = *(const bf16x8*)Wb;
  cw[1] = *(const bf16x8*)(Wb + (size_t)16 * HDIM);
#pragma unroll
  for (int kb = 0; kb < 8; ++kb) {
    bf16x8 na[2], nw[2];
    if (kb < 7) {
      const int off = (kb + 1) * 32;
      na[0] = *(const bf16x8*)(Ab + off);
      na[1] = *(const bf16x8*)(Ab + (size_t)16 * HDIM + off);
      nw[0] = *(const bf16x8*)(Wb + off);
      nw[1] = *(const bf16x8*)(Wb + (size_t)16 * HDIM + off);
    }
#pragma unroll
    for (int mi = 0; mi < 2; ++mi)
#pragma unroll
      for (int ni = 0; ni < 2; ++ni)
        acc[mi][ni] = __builtin_amdgcn_mfma_f32_16x16x32_bf16(
            ca[mi], cw[ni], acc[mi][ni], 0, 0, 0);
    if (kb < 7) {
      ca[0] = na[0]; ca[1] = na[1];
      cw[0] = nw[0]; cw[1] = nw[1];
    }
  }
  const int crow = (lane >> 4) * 4;
  const int ccol = lane & 15;
#pragma unroll
  for (int mi = 0; mi < 2; ++mi)
#pragma unroll
    for (int ni = 0; ni < 2; ++ni) {
      const int oc = col0 + ni * 16 + ccol;
      const float bv = bias[oc];
#pragma unroll
      for (int rg = 0; rg < 4; ++rg)
        out[(size_t)(row0 + mi * 16 + crow + rg) * HDIM + oc] = acc[mi][ni][rg] + bv;
    }
}

extern "C" void kernel_launch(void* const* d_in, const int* in_sizes, int n_in,
                              void* d_out, int out_size, void* d_ws, size_t ws_size,
                              hipStream_t stream) {
  const float* query = (const float*)d_in[0];
  const float* key   = (const float*)d_in[1];
  const float* value = (const float*)d_in[2];
  const int*   graph = (const int*)d_in[3];
  const float* ekt   = (const float*)d_in[4];
  const float* evt   = (const float*)d_in[5];
  const float* eqt   = (const float*)d_in[6];
  const float* Wq = (const float*)d_in[7];  const float* bq = (const float*)d_in[8];
  const float* Wk = (const float*)d_in[9];  const float* bk = (const float*)d_in[10];
  const float* Wv = (const float*)d_in[11]; const float* bv = (const float*)d_in[12];
  const float* Wo = (const float*)d_in[13]; const float* bo = (const float*)d_in[14];
  float* out = (float*)d_out;

  const size_t NE = (size_t)NTOK * HDIM;   // 1,040,384 elems
  char* p = (char*)d_ws;
  __bf16* qpb = (__bf16*)p;         p += NE * 2;
  __bf16* kpb = (__bf16*)p;         p += NE * 2;
  __bf16* vpb = (__bf16*)p;         p += NE * 2;
  __bf16* xpb = (__bf16*)p;         p += NE * 2;
  __bf16* Wqb = (__bf16*)p;         p += (size_t)HDIM * HDIM * 2;
  __bf16* Wkb = (__bf16*)p;         p += (size_t)HDIM * HDIM * 2;
  __bf16* Wvb = (__bf16*)p;         p += (size_t)HDIM * HDIM * 2;
  __bf16* Wob = (__bf16*)p;

  convert_w<<<dim3(256), 256, 0, stream>>>(Wq, Wk, Wv, Wo, Wqb, Wkb, Wvb, Wob);
  gemm_qkv<<<dim3(127, 3), 256, 0, stream>>>(query, key, value,
                                             Wqb, bq, Wkb, bk, Wvb, bv,
                                             qpb, kpb, vpb);
  attn_x<<<dim3(96 + 992), 256, 0, stream>>>(qpb, kpb, vpb, graph,
                                             ekt, evt, eqt, xpb);
  gemm_o<<<dim3(32, 8), 256, 0, stream>>>(xpb, Wob, bo, out);
}

// Round 12
// 56.564 us; speedup vs baseline: 1.5012x; 1.0003x over previous
//
#include <hip/hip_runtime.h>
#include <hip/hip_bf16.h>

#define S_LEN 127
#define NB    32
#define HDIM  256
#define DH    64
#define SCALE_F 0.125f
#define NEG_F  -100000.0f

typedef __bf16 bf16x8 __attribute__((ext_vector_type(8)));
typedef __bf16 bf16x4 __attribute__((ext_vector_type(4)));
typedef float  f32x4  __attribute__((ext_vector_type(4)));

#define NTOK  4064                 // NB * S_LEN
#define NW4   16384                // 256*256/4 float4 groups per W

__device__ __forceinline__ float4 b2f4(bf16x4 v) {
  return make_float4((float)v[0], (float)v[1], (float)v[2], (float)v[3]);
}

// ---------------------------------------------------------------------------
// W-only f32 -> bf16 conversion (R8-proven).
// ---------------------------------------------------------------------------
__global__ __launch_bounds__(256) void convert_w(
    const float* __restrict__ Wq, const float* __restrict__ Wk,
    const float* __restrict__ Wv, const float* __restrict__ Wo,
    __bf16* __restrict__ Wqb, __bf16* __restrict__ Wkb,
    __bf16* __restrict__ Wvb, __bf16* __restrict__ Wob)
{
  size_t t = (size_t)blockIdx.x * 256 + threadIdx.x;   // float4 index
  const float* src; __bf16* dst;
  if (t < NW4)                 { src = Wq; dst = Wqb; }
  else if ((t -= NW4) < NW4)   { src = Wk; dst = Wkb; }
  else if ((t -= NW4) < NW4)   { src = Wv; dst = Wvb; }
  else { t -= NW4;               src = Wo; dst = Wob; }
  const float4 x = ((const float4*)src)[t];
  bf16x4 r;
  r[0] = (__bf16)x.x; r[1] = (__bf16)x.y; r[2] = (__bf16)x.z; r[3] = (__bf16)x.w;
  ((bf16x4*)dst)[t] = r;
}

// ---------------------------------------------------------------------------
// q/k/v projection with in-LDS A conversion (R8-proven). grid (127,3), 256 thr.
// ---------------------------------------------------------------------------
__global__ __launch_bounds__(256) void gemm_qkv(
    const float* __restrict__ q_in, const float* __restrict__ k_in,
    const float* __restrict__ v_in,
    const __bf16* __restrict__ Wqb, const float* __restrict__ bq,
    const __bf16* __restrict__ Wkb, const float* __restrict__ bk,
    const __bf16* __restrict__ Wvb, const float* __restrict__ bv,
    __bf16* __restrict__ qpb, __bf16* __restrict__ kpb, __bf16* __restrict__ vpb)
{
  const int tile = blockIdx.x;       // 0..126
  const float* A; const __bf16* W; const float* bias; __bf16* o;
  if (blockIdx.y == 0)      { A = q_in; W = Wqb; bias = bq; o = qpb; }
  else if (blockIdx.y == 1) { A = k_in; W = Wkb; bias = bk; o = kpb; }
  else                      { A = v_in; W = Wvb; bias = bv; o = vpb; }

  __shared__ __bf16 sA[32][264];
  const int row0 = tile * 32;

#pragma unroll
  for (int j = 0; j < 8; ++j) {
    const int f = threadIdx.x + j * 256;   // 0..2047
    const int rr = f >> 6, c4 = f & 63;
    const float4 x = *(const float4*)(A + (size_t)(row0 + rr) * HDIM + c4 * 4);
    __bf16* d = &sA[rr][c4 * 4];
    d[0] = (__bf16)x.x; d[1] = (__bf16)x.y; d[2] = (__bf16)x.z; d[3] = (__bf16)x.w;
  }
  __syncthreads();

  const int w    = threadIdx.x >> 6;
  const int lane = threadIdx.x & 63;
  const int r    = lane & 15;
  const int ksl  = (lane >> 4) << 3;
  const int wc   = w * 64;

  const __bf16* Wb = W + (size_t)(wc + r) * HDIM + ksl;
  f32x4 acc[2][4] = {};

  bf16x8 cw[4];
#pragma unroll
  for (int ni = 0; ni < 4; ++ni)
    cw[ni] = *(const bf16x8*)(Wb + (size_t)ni * 16 * HDIM);
#pragma unroll
  for (int kb = 0; kb < 8; ++kb) {
    bf16x8 nw[4];
    if (kb < 7) {
#pragma unroll
      for (int ni = 0; ni < 4; ++ni)
        nw[ni] = *(const bf16x8*)(Wb + (size_t)ni * 16 * HDIM + (kb + 1) * 32);
    }
    const bf16x8 a0 = *(const bf16x8*)&sA[r][kb * 32 + ksl];
    const bf16x8 a1 = *(const bf16x8*)&sA[16 + r][kb * 32 + ksl];
#pragma unroll
    for (int ni = 0; ni < 4; ++ni) {
      acc[0][ni] = __builtin_amdgcn_mfma_f32_16x16x32_bf16(a0, cw[ni], acc[0][ni], 0, 0, 0);
      acc[1][ni] = __builtin_amdgcn_mfma_f32_16x16x32_bf16(a1, cw[ni], acc[1][ni], 0, 0, 0);
    }
    if (kb < 7) {
#pragma unroll
      for (int ni = 0; ni < 4; ++ni) cw[ni] = nw[ni];
    }
  }
  const int crow = (lane >> 4) * 4;
  const int ccol = lane & 15;
#pragma unroll
  for (int mi = 0; mi < 2; ++mi)
#pragma unroll
    for (int ni = 0; ni < 4; ++ni) {
      const int oc = wc + ni * 16 + ccol;
      const float bv = bias[oc];
#pragma unroll
      for (int rg = 0; rg < 4; ++rg)
        o[(size_t)(row0 + mi * 16 + crow + rg) * HDIM + oc] =
            (__bf16)(acc[mi][ni][rg] + bv);
    }
}

// ---------------------------------------------------------------------------
// Attention. Grid 1088 x 256:
//  blocks 0..95   : one block per q<3 item (127 cols, LDS softmax).
//  blocks 96..1087: one WAVE per q>=3 item. Straight-line, no LDS, no
//                   __syncthreads: all 5 candidate columns' loads issued
//                   unconditionally up front (always in-bounds), full-wave
//                   butterfly score reduce, in-register softmax-of-5,
//                   mask via wave-uniform bits. mask5==0 -> uniform 1/127.
// ---------------------------------------------------------------------------
__global__ __launch_bounds__(256) void attn_x(
    const __bf16* __restrict__ qpb, const __bf16* __restrict__ kpb,
    const __bf16* __restrict__ vpb, const int* __restrict__ graph,
    const float* __restrict__ ekt, const float* __restrict__ evt,
    const float* __restrict__ eqt, __bf16* __restrict__ xpb)
{
  const int w  = threadIdx.x >> 6;   // wave 0..3
  const int l  = threadIdx.x & 63;   // lane

  if (blockIdx.x >= 96) {
    // ================= q>=3 path: one wave per item, d = lane ============
    const int widx = (blockIdx.x - 96) * 4 + w;      // 0..3967
    const int b = widx / 124;
    const int q = 3 + widx % 124;
    const int blk = 3 + 2 * ((q - 3) >> 1);
    const int c3 = blk, c4c = blk + 1;               // always <= 126

    bool gb = false;
    if (l < 5) {
      const int c = (l < 3) ? l : ((l == 3) ? c3 : c4c);
      gb = graph[((size_t)b * S_LEN + q) * S_LEN + c] != 0;
    }
    const unsigned mask5 = (unsigned)(__ballot(gb) & 31ull);

    const float* eqb2 = eqt + ((size_t)b * S_LEN * S_LEN + q) * DH;
    const float* ekb2 = ekt + ((size_t)(b * S_LEN + q)) * S_LEN * DH;
    const float* evb2 = evt + ((size_t)(b * S_LEN + q)) * S_LEN * DH;
    const __bf16* kpbb = kpb + (size_t)b * S_LEN * HDIM;
    const __bf16* vpbb = vpb + (size_t)b * S_LEN * HDIM;
    const __bf16* qrow = qpb + ((size_t)b * S_LEN + q) * HDIM;

    float acc0 = 0.f, acc1 = 0.f, acc2 = 0.f, acc3 = 0.f;

    if (mask5) {
      const int cols[5] = {0, 1, 2, c3, c4c};
      // ---- issue ALL loads up front (independent; 1-2 latency rounds) ----
      float qv[4];
#pragma unroll
      for (int h = 0; h < 4; ++h) qv[h] = (float)qrow[h * 64 + l];
      float eqv[5], ekv[5], evv[5], kv[5][4], vv[5][4];
#pragma unroll
      for (int ci = 0; ci < 5; ++ci) {
        const int c = cols[ci];
        eqv[ci] = eqb2[(size_t)c * (S_LEN * DH) + l];
        ekv[ci] = ekb2[(size_t)c * DH + l];
        evv[ci] = evb2[(size_t)c * DH + l];
        const __bf16* kr = kpbb + (size_t)c * HDIM + l;
        const __bf16* vr = vpbb + (size_t)c * HDIM + l;
#pragma unroll
        for (int h = 0; h < 4; ++h) {
          kv[ci][h] = (float)kr[h * 64];
          vv[ci][h] = (float)vr[h * 64];
        }
      }
      // ---- scores: full-wave butterfly allreduce per (col, head) ----
      float s[4][5];
#pragma unroll
      for (int ci = 0; ci < 5; ++ci)
#pragma unroll
        for (int h = 0; h < 4; ++h) {
          float p = (qv[h] + eqv[ci]) * (kv[ci][h] + ekv[ci]);
#pragma unroll
          for (int off = 1; off < 64; off <<= 1) p += __shfl_xor(p, off, 64);
          s[h][ci] = p * SCALE_F;
        }
      // ---- softmax over valid cols (wave-uniform mask bits) + PV ----
#pragma unroll
      for (int h = 0; h < 4; ++h) {
        float m = -INFINITY;
#pragma unroll
        for (int ci = 0; ci < 5; ++ci)
          if ((mask5 >> ci) & 1) m = fmaxf(m, s[h][ci]);
        float e[5], sum = 0.f;
#pragma unroll
        for (int ci = 0; ci < 5; ++ci) {
          e[ci] = ((mask5 >> ci) & 1) ? expf(s[h][ci] - m) : 0.f;
          sum += e[ci];
        }
        const float inv = 1.0f / sum;
        float a = 0.f;
#pragma unroll
        for (int ci = 0; ci < 5; ++ci)
          a += (e[ci] * inv) * (vv[ci][h] + evv[ci]);
        if (h == 0) acc0 = a; else if (h == 1) acc1 = a;
        else if (h == 2) acc2 = a; else acc3 = a;
      }
    } else {
      // all candidates masked -> uniform 1/127 over all 127 columns
#pragma unroll 4
      for (int c = 0; c < S_LEN; ++c) {
        const float ev = evb2[(size_t)c * DH + l];
        const __bf16* vr = vpbb + (size_t)c * HDIM + l;
        acc0 += (float)vr[0]   + ev;
        acc1 += (float)vr[64]  + ev;
        acc2 += (float)vr[128] + ev;
        acc3 += (float)vr[192] + ev;
      }
      const float u = 1.0f / 127.0f;
      acc0 *= u; acc1 *= u; acc2 *= u; acc3 *= u;
    }

    __bf16* xr = xpb + ((size_t)b * S_LEN + q) * HDIM;
    xr[l]       = (__bf16)acc0;
    xr[64 + l]  = (__bf16)acc1;
    xr[128 + l] = (__bf16)acc2;
    xr[192 + l] = (__bf16)acc3;
    return;
  }

  // ================= q<3 path: block per item, 127 columns ===============
  const int ll = l & 15;             // d-subgroup (score phase)
  const int g  = l >> 4;             // column slot (score phase)

  __shared__ float s_attn[4][S_LEN];
  __shared__ float s_mskf[S_LEN];

  const int b = blockIdx.x / 3, q = blockIdx.x % 3;

  if (w < 2) {
    const int k0 = w * 64 + l;
    if (k0 < S_LEN)
      s_mskf[k0] = (graph[((size_t)b * S_LEN + q) * S_LEN + k0] != 0) ? 1.f : 0.f;
  }
  __syncthreads();

  // ---- scores over all 127 columns, direct addressing ----
  const __bf16* qrow = qpb + ((size_t)b * S_LEN + q) * HDIM;
  float4 q4[4];
#pragma unroll
  for (int h = 0; h < 4; ++h)
    q4[h] = b2f4(*(const bf16x4*)(qrow + h * 64 + ll * 4));
  const float* eqb2 = eqt + ((size_t)b * S_LEN * S_LEN + q) * DH;
  const float* ekb2 = ekt + ((size_t)(b * S_LEN + q)) * S_LEN * DH;
  const __bf16* kpbb = kpb + (size_t)b * S_LEN * HDIM;

  for (int i0 = 0; i0 < S_LEN; i0 += 16) {
    const int i = i0 + w * 4 + g;
    float p0 = 0.f, p1 = 0.f, p2 = 0.f, p3 = 0.f;
    if (i < S_LEN) {
      const float4 eq4 = *(const float4*)(eqb2 + (size_t)i * (S_LEN * DH) + ll * 4);
      const float4 ek4 = *(const float4*)(ekb2 + (size_t)i * DH + ll * 4);
      const __bf16* kr = kpbb + (size_t)i * HDIM + ll * 4;
      const float4 k0f = b2f4(*(const bf16x4*)(kr));
      const float4 k1f = b2f4(*(const bf16x4*)(kr + 64));
      const float4 k2f = b2f4(*(const bf16x4*)(kr + 128));
      const float4 k3f = b2f4(*(const bf16x4*)(kr + 192));
      p0 = (q4[0].x+eq4.x)*(k0f.x+ek4.x) + (q4[0].y+eq4.y)*(k0f.y+ek4.y)
         + (q4[0].z+eq4.z)*(k0f.z+ek4.z) + (q4[0].w+eq4.w)*(k0f.w+ek4.w);
      p1 = (q4[1].x+eq4.x)*(k1f.x+ek4.x) + (q4[1].y+eq4.y)*(k1f.y+ek4.y)
         + (q4[1].z+eq4.z)*(k1f.z+ek4.z) + (q4[1].w+eq4.w)*(k1f.w+ek4.w);
      p2 = (q4[2].x+eq4.x)*(k2f.x+ek4.x) + (q4[2].y+eq4.y)*(k2f.y+ek4.y)
         + (q4[2].z+eq4.z)*(k2f.z+ek4.z) + (q4[2].w+eq4.w)*(k2f.w+ek4.w);
      p3 = (q4[3].x+eq4.x)*(k3f.x+ek4.x) + (q4[3].y+eq4.y)*(k3f.y+ek4.y)
         + (q4[3].z+eq4.z)*(k3f.z+ek4.z) + (q4[3].w+eq4.w)*(k3f.w+ek4.w);
    }
#pragma unroll
    for (int off = 1; off < 16; off <<= 1) {
      p0 += __shfl_xor(p0, off, 64);
      p1 += __shfl_xor(p1, off, 64);
      p2 += __shfl_xor(p2, off, 64);
      p3 += __shfl_xor(p3, off, 64);
    }
    if (i < S_LEN && ll < 4) {
      const float sc = (ll == 0) ? p0 : (ll == 1) ? p1 : (ll == 2) ? p2 : p3;
      s_attn[ll][i] = (s_mskf[i] != 0.f) ? sc * SCALE_F : NEG_F;
    }
  }
  __syncthreads();

  // ---- softmax per head over 127 ----
  {
    const float v0 = (l < S_LEN) ? s_attn[w][l] : -INFINITY;
    const float v1 = (64 + l < S_LEN) ? s_attn[w][64 + l] : -INFINITY;
    float mx = fmaxf(v0, v1);
#pragma unroll
    for (int off = 32; off; off >>= 1) mx = fmaxf(mx, __shfl_xor(mx, off, 64));
    const float e0 = (l < S_LEN) ? expf(v0 - mx) : 0.f;
    const float e1 = (64 + l < S_LEN) ? expf(v1 - mx) : 0.f;
    float sm = e0 + e1;
#pragma unroll
    for (int off = 32; off; off >>= 1) sm += __shfl_xor(sm, off, 64);
    const float inv = 1.0f / sm;
    if (l < S_LEN) s_attn[w][l] = e0 * inv;
    if (64 + l < S_LEN) s_attn[w][64 + l] = e1 * inv;
  }
  __syncthreads();

  // ---- PV over 127: unroll-8, independent loads, compiler-pipelined ----
  {
    const float* evb2 = evt + ((size_t)(b * S_LEN + q)) * S_LEN * DH;
    const __bf16* vbp = vpb + (size_t)b * S_LEN * HDIM + w * DH + ll * 4;
    float ax = 0.f, ay = 0.f, az = 0.f, aw2 = 0.f;
#pragma unroll 8
    for (int i = g; i < S_LEN; i += 4) {
      const float a = s_attn[w][i];
      const float4 vf = b2f4(*(const bf16x4*)(vbp + (size_t)i * HDIM));
      const float4 e4 = *(const float4*)(evb2 + (size_t)i * DH + ll * 4);
      ax  += a * (vf.x + e4.x);
      ay  += a * (vf.y + e4.y);
      az  += a * (vf.z + e4.z);
      aw2 += a * (vf.w + e4.w);
    }
#pragma unroll
    for (int off = 16; off < 64; off <<= 1) {
      ax  += __shfl_xor(ax, off, 64);
      ay  += __shfl_xor(ay, off, 64);
      az  += __shfl_xor(az, off, 64);
      aw2 += __shfl_xor(aw2, off, 64);
    }
    if (g == 0) {
      bf16x4 rr;
      rr[0] = (__bf16)ax; rr[1] = (__bf16)ay;
      rr[2] = (__bf16)az; rr[3] = (__bf16)aw2;
      *(bf16x4*)(xpb + ((size_t)b * S_LEN + q) * HDIM + w * 64 + ll * 4) = rr;
    }
  }
}

// ---------------------------------------------------------------------------
// Output projection (R8-proven): per-wave 32x32 tile, bf16 A and W.
// ---------------------------------------------------------------------------
__global__ __launch_bounds__(256) void gemm_o(
    const __bf16* __restrict__ A, const __bf16* __restrict__ W,
    const float* __restrict__ bias, float* __restrict__ out)
{
  const int w = threadIdx.x >> 6;
  const int tile = blockIdx.x * 4 + w;
  if (tile >= 127) return;
  const int row0 = tile * 32, col0 = blockIdx.y * 32;
  const int lane = threadIdx.x & 63;
  const int r  = lane & 15;
  const int ks = (lane >> 4) << 3;
  const __bf16* Ab = A + (size_t)(row0 + r) * HDIM + ks;
  const __bf16* Wb = W + (size_t)(col0 + r) * HDIM + ks;
  f32x4 acc[2][2] = {};

  bf16x8 ca[2], cw[2];
  ca[0] = *(const bf16x8*)Ab;
  ca[1] = *(const bf16x8*)(Ab + (size_t)16 * HDIM);
  cw[0] = *(const bf16x8*)Wb;
  cw[1] = *(const bf16x8*)(Wb + (size_t)16 * HDIM);
#pragma unroll
  for (int kb = 0; kb < 8; ++kb) {
    bf16x8 na[2], nw[2];
    if (kb < 7) {
      const int off = (kb + 1) * 32;
      na[0] = *(const bf16x8*)(Ab + off);
      na[1] = *(const bf16x8*)(Ab + (size_t)16 * HDIM + off);
      nw[0] = *(const bf16x8*)(Wb + off);
      nw[1] = *(const bf16x8*)(Wb + (size_t)16 * HDIM + off);
    }
#pragma unroll
    for (int mi = 0; mi < 2; ++mi)
#pragma unroll
      for (int ni = 0; ni < 2; ++ni)
        acc[mi][ni] = __builtin_amdgcn_mfma_f32_16x16x32_bf16(
            ca[mi], cw[ni], acc[mi][ni], 0, 0, 0);
    if (kb < 7) {
      ca[0] = na[0]; ca[1] = na[1];
      cw[0] = nw[0]; cw[1] = nw[1];
    }
  }
  const int crow = (lane >> 4) * 4;
  const int ccol = lane & 15;
#pragma unroll
  for (int mi = 0; mi < 2; ++mi)
#pragma unroll
    for (int ni = 0; ni < 2; ++ni) {
      const int oc = col0 + ni * 16 + ccol;
      const float bv = bias[oc];
#pragma unroll
      for (int rg = 0; rg < 4; ++rg)
        out[(size_t)(row0 + mi * 16 + crow + rg) * HDIM + oc] = acc[mi][ni][rg] + bv;
    }
}

extern "C" void kernel_launch(void* const* d_in, const int* in_sizes, int n_in,
                              void* d_out, int out_size, void* d_ws, size_t ws_size,
                              hipStream_t stream) {
  const float* query = (const float*)d_in[0];
  const float* key   = (const float*)d_in[1];
  const float* value = (const float*)d_in[2];
  const int*   graph = (const int*)d_in[3];
  const float* ekt   = (const float*)d_in[4];
  const float* evt   = (const float*)d_in[5];
  const float* eqt   = (const float*)d_in[6];
  const float* Wq = (const float*)d_in[7];  const float* bq = (const float*)d_in[8];
  const float* Wk = (const float*)d_in[9];  const float* bk = (const float*)d_in[10];
  const float* Wv = (const float*)d_in[11]; const float* bv = (const float*)d_in[12];
  const float* Wo = (const float*)d_in[13]; const float* bo = (const float*)d_in[14];
  float* out = (float*)d_out;

  const size_t NE = (size_t)NTOK * HDIM;   // 1,040,384 elems
  char* p = (char*)d_ws;
  __bf16* qpb = (__bf16*)p;         p += NE * 2;
  __bf16* kpb = (__bf16*)p;         p += NE * 2;
  __bf16* vpb = (__bf16*)p;         p += NE * 2;
  __bf16* xpb = (__bf16*)p;         p += NE * 2;
  __bf16* Wqb = (__bf16*)p;         p += (size_t)HDIM * HDIM * 2;
  __bf16* Wkb = (__bf16*)p;         p += (size_t)HDIM * HDIM * 2;
  __bf16* Wvb = (__bf16*)p;         p += (size_t)HDIM * HDIM * 2;
  __bf16* Wob = (__bf16*)p;

  convert_w<<<dim3(256), 256, 0, stream>>>(Wq, Wk, Wv, Wo, Wqb, Wkb, Wvb, Wob);
  gemm_qkv<<<dim3(127, 3), 256, 0, stream>>>(query, key, value,
                                             Wqb, bq, Wkb, bk, Wvb, bv,
                                             qpb, kpb, vpb);
  attn_x<<<dim3(96 + 992), 256, 0, stream>>>(qpb, kpb, vpb, graph,
                                             ekt, evt, eqt, xpb);
  gemm_o<<<dim3(32, 8), 256, 0, stream>>>(xpb, Wob, bo, out);
}